// Round 3
// baseline (7825.410 us; speedup 1.0000x reference)
//
#include <hip/hip_runtime.h>
#include <math.h>

#define N_NODES 100000
#define N_EDGES 1600000
#define DIM     128
#define NLAYER  5
#define NGRAPH  128
#define NTASK   10
#define NBOND   4
#define BN_EPS  1e-5f

// ---------------------------------------------------------------- histograms
__global__ __launch_bounds__(256) void hist_kernel(
    const int* __restrict__ row, const int* __restrict__ col,
    int* __restrict__ cnt_row, int* __restrict__ cnt_col) {
  int i = blockIdx.x * blockDim.x + threadIdx.x;
  int stride = gridDim.x * blockDim.x;
  for (; i < N_EDGES; i += stride) {
    atomicAdd(&cnt_row[row[i]], 1);
    atomicAdd(&cnt_col[col[i]], 1);
  }
}

__global__ __launch_bounds__(256) void deg_kernel(
    const int* __restrict__ cnt_row, float* __restrict__ deg, float* __restrict__ dinv) {
  int i = blockIdx.x * blockDim.x + threadIdx.x;
  if (i < N_NODES) {
    float d = (float)cnt_row[i] + 1.0f;
    deg[i] = d;
    dinv[i] = rsqrtf(d);
  }
}

// ---------------------------------------------------------------- scan (CSR offsets)
__global__ __launch_bounds__(256) void scan1_kernel(
    const int* __restrict__ cnt, int* __restrict__ excl, int* __restrict__ bsum) {
  __shared__ int s[256];
  int t = threadIdx.x;
  int i = blockIdx.x * 256 + t;
  int v = (i < N_NODES) ? cnt[i] : 0;
  s[t] = v;
  __syncthreads();
  for (int off = 1; off < 256; off <<= 1) {
    int add = (t >= off) ? s[t - off] : 0;
    __syncthreads();
    s[t] += add;
    __syncthreads();
  }
  if (i < N_NODES) excl[i] = s[t] - v;   // exclusive within block
  if (t == 255) bsum[blockIdx.x] = s[255];
}

__global__ __launch_bounds__(512) void scan2_kernel(
    const int* __restrict__ bsum, int* __restrict__ bexcl, int nb) {
  __shared__ int s[512];
  int t = threadIdx.x;
  int v = (t < nb) ? bsum[t] : 0;
  s[t] = v;
  __syncthreads();
  for (int off = 1; off < 512; off <<= 1) {
    int add = (t >= off) ? s[t - off] : 0;
    __syncthreads();
    s[t] += add;
    __syncthreads();
  }
  if (t < nb) bexcl[t] = s[t] - v;
}

__global__ __launch_bounds__(256) void scan3_kernel(
    int* __restrict__ excl, const int* __restrict__ bexcl) {
  int i = blockIdx.x * 256 + threadIdx.x;
  if (i < N_NODES) excl[i] += bexcl[blockIdx.x];
  if (i == 0) excl[N_NODES] = N_EDGES;
}

// ---------------------------------------------------------------- CSR scatter
__global__ __launch_bounds__(256) void scatter_kernel(
    const int* __restrict__ row, const int* __restrict__ col,
    const int* __restrict__ attr, const int* __restrict__ csr_off,
    int* __restrict__ pos, const float* __restrict__ dinv,
    int* __restrict__ src_pack, float* __restrict__ enorm) {
  int e = blockIdx.x * blockDim.x + threadIdx.x;
  int stride = gridDim.x * blockDim.x;
  for (; e < N_EDGES; e += stride) {
    int d = col[e];
    int s = row[e];
    int p = csr_off[d] + atomicAdd(&pos[d], 1);
    src_pack[p] = s | (attr[e] << 20);         // src < 2^20, attr < 4
    enorm[p] = dinv[s] * dinv[d];
  }
}

// ---------------------------------------------------------------- GEMM: hx = act(hin) @ W + b
// Explicit 2D register-tiled LDS GEMM. Block = 256 threads computes a
// 128-row x 128-col output tile; K=128 split into two 64-wide phases.
// LDS: hs (128 rows x 16 f4 slots, XOR-swizzled by row&3) + Ws (64k x 32 f4)
// = exactly 64 KB -> 2 blocks/CU. Per-thread tile 8 rows x 8 cols:
// 16 ds_read_b128 feed 1024 FMAs per k4 group of 4 -> LDS-pipe cost ~4x
// lower per FLOP than the broadcast structure. BN scale/shift + relu of the
// previous layer fused into the h staging (useact). FMA order: init=bias,
// k strictly ascending -> bit-identical to prior rounds.
#define GBM 128
__global__ __launch_bounds__(256, 2) void gemm_kernel(
    const float* __restrict__ hin, const float* __restrict__ W,
    const float* __restrict__ bias, const float* __restrict__ scale,
    const float* __restrict__ shift, int useact,
    float* __restrict__ hx, float* __restrict__ bnzero) {
  __shared__ float4 lds[4096];          // [0..2047]=hs, [2048..4095]=Ws
  float4* hs = lds;
  float4* Ws = lds + 2048;
  int t = threadIdx.x;
  if (blockIdx.x == 0) {                // zero BN accumulators for this layer
    ((float*)0, 0);                     // no-op
    bnzero[t] = 0.0f;
  }
  int cg = t & 15;                      // column group: cols 4cg..4cg+3 and 64+4cg..
  int rg = t >> 4;                      // row group: rows rg, rg+16, ..., rg+112
  int cr = rg & 3;                      // hs swizzle constant for this thread
  int r0 = blockIdx.x * GBM;
  if (r0 > N_NODES - GBM) r0 = N_NODES - GBM;   // tail overlap (benign dup stores)

  // act params for this thread's staged k-slots (slot s = t&15 is constant)
  float scA[4], shA[4], scB[4], shB[4];
  if (useact) {
    int kb = cg * 4;
#pragma unroll
    for (int j = 0; j < 4; j++) {
      scA[j] = scale[kb + j];       shA[j] = shift[kb + j];
      scB[j] = scale[64 + kb + j];  shB[j] = shift[64 + kb + j];
    }
  }
  // bias for this thread's 8 columns
  float b0[4], b1[4];
#pragma unroll
  for (int j = 0; j < 4; j++) {
    b0[j] = bias[4 * cg + j];
    b1[j] = bias[64 + 4 * cg + j];
  }

  const float4* hg = (const float4*)hin;
  const float4* wg = (const float4*)W;
  float4 ph[8], pw[8];
  // prefetch phase A (h k 0..63 of this row tile; W rows 0..63)
#pragma unroll
  for (int it = 0; it < 8; it++) {
    int u = t + it * 256;
    ph[it] = hg[(size_t)(r0 + (u >> 4)) * 32 + (u & 15)];
    pw[it] = wg[(u >> 5) * 32 + (u & 31)];
  }

  float acc0[8][4], acc1[8][4];
#pragma unroll
  for (int i = 0; i < 8; i++)
#pragma unroll
    for (int j = 0; j < 4; j++) { acc0[i][j] = b0[j]; acc1[i][j] = b1[j]; }

  // ---- phase A: stage LDS
#pragma unroll
  for (int it = 0; it < 8; it++) {
    int u = t + it * 256;
    float4 v = ph[it];
    if (useact) {
      v.x = fmaxf(fmaf(v.x, scA[0], shA[0]), 0.f);
      v.y = fmaxf(fmaf(v.y, scA[1], shA[1]), 0.f);
      v.z = fmaxf(fmaf(v.z, scA[2], shA[2]), 0.f);
      v.w = fmaxf(fmaf(v.w, scA[3], shA[3]), 0.f);
    }
    int lrow = u >> 4, s = u & 15;
    hs[lrow * 16 + (s ^ (lrow & 3))] = v;
    Ws[u] = pw[it];
  }
  __syncthreads();
  // prefetch phase B while computing A
#pragma unroll
  for (int it = 0; it < 8; it++) {
    int u = t + it * 256;
    ph[it] = hg[(size_t)(r0 + (u >> 4)) * 32 + 16 + (u & 15)];
    pw[it] = wg[(64 + (u >> 5)) * 32 + (u & 31)];
  }
  // ---- compute k = 0..63
#pragma unroll
  for (int k4 = 0; k4 < 16; k4++) {
    float4 hf[8];
    int soff = k4 ^ cr;
#pragma unroll
    for (int i = 0; i < 8; i++) hf[i] = hs[(rg + 16 * i) * 16 + soff];
#pragma unroll
    for (int kk = 0; kk < 4; kk++) {
      float4 w0 = Ws[(k4 * 4 + kk) * 32 + cg];
      float4 w1 = Ws[(k4 * 4 + kk) * 32 + 16 + cg];
#pragma unroll
      for (int i = 0; i < 8; i++) {
        float hv = ((const float*)&hf[i])[kk];
        acc0[i][0] = fmaf(hv, w0.x, acc0[i][0]);
        acc0[i][1] = fmaf(hv, w0.y, acc0[i][1]);
        acc0[i][2] = fmaf(hv, w0.z, acc0[i][2]);
        acc0[i][3] = fmaf(hv, w0.w, acc0[i][3]);
        acc1[i][0] = fmaf(hv, w1.x, acc1[i][0]);
        acc1[i][1] = fmaf(hv, w1.y, acc1[i][1]);
        acc1[i][2] = fmaf(hv, w1.z, acc1[i][2]);
        acc1[i][3] = fmaf(hv, w1.w, acc1[i][3]);
      }
    }
  }
  __syncthreads();
  // ---- phase B: stage LDS
#pragma unroll
  for (int it = 0; it < 8; it++) {
    int u = t + it * 256;
    float4 v = ph[it];
    if (useact) {
      v.x = fmaxf(fmaf(v.x, scB[0], shB[0]), 0.f);
      v.y = fmaxf(fmaf(v.y, scB[1], shB[1]), 0.f);
      v.z = fmaxf(fmaf(v.z, scB[2], shB[2]), 0.f);
      v.w = fmaxf(fmaf(v.w, scB[3], shB[3]), 0.f);
    }
    int lrow = u >> 4, s = u & 15;
    hs[lrow * 16 + (s ^ (lrow & 3))] = v;
    Ws[u] = pw[it];
  }
  __syncthreads();
  // ---- compute k = 64..127
#pragma unroll
  for (int k4 = 0; k4 < 16; k4++) {
    float4 hf[8];
    int soff = k4 ^ cr;
#pragma unroll
    for (int i = 0; i < 8; i++) hf[i] = hs[(rg + 16 * i) * 16 + soff];
#pragma unroll
    for (int kk = 0; kk < 4; kk++) {
      float4 w0 = Ws[(k4 * 4 + kk) * 32 + cg];
      float4 w1 = Ws[(k4 * 4 + kk) * 32 + 16 + cg];
#pragma unroll
      for (int i = 0; i < 8; i++) {
        float hv = ((const float*)&hf[i])[kk];
        acc0[i][0] = fmaf(hv, w0.x, acc0[i][0]);
        acc0[i][1] = fmaf(hv, w0.y, acc0[i][1]);
        acc0[i][2] = fmaf(hv, w0.z, acc0[i][2]);
        acc0[i][3] = fmaf(hv, w0.w, acc0[i][3]);
        acc1[i][0] = fmaf(hv, w1.x, acc1[i][0]);
        acc1[i][1] = fmaf(hv, w1.y, acc1[i][1]);
        acc1[i][2] = fmaf(hv, w1.z, acc1[i][2]);
        acc1[i][3] = fmaf(hv, w1.w, acc1[i][3]);
      }
    }
  }
  // ---- store
  float4* ox = (float4*)hx;
#pragma unroll
  for (int i = 0; i < 8; i++) {
    int grow = r0 + rg + 16 * i;
    float4 s0, s1;
    s0.x = acc0[i][0]; s0.y = acc0[i][1]; s0.z = acc0[i][2]; s0.w = acc0[i][3];
    s1.x = acc1[i][0]; s1.y = acc1[i][1]; s1.z = acc1[i][2]; s1.w = acc1[i][3];
    ox[(size_t)grow * 32 + cg] = s0;
    ox[(size_t)grow * 32 + 16 + cg] = s1;
  }
}

// ---------------------------------------------------------------- edge aggregation
// One wave per destination node; lane&31 owns features [4q..4q+3] via float4.
// Two 32-lane halves process two edge streams; each half unrolled 4x ->
// 8 independent 512B row gathers in flight per wave. Halves combined via
// shfl_xor(32). BN partials: LDS block reduce -> one global atomic/feature.
__global__ __launch_bounds__(256) void agg_kernel(
    const float* __restrict__ hx, const int* __restrict__ csr_off,
    const int* __restrict__ src_pack, const float* __restrict__ enorm,
    const float* __restrict__ bond, const float* __restrict__ root,
    const float* __restrict__ deg, float* __restrict__ h2,
    float* __restrict__ bnbuf) {
  __shared__ float4 bondS[NBOND * 32];
  __shared__ float4 rootS[32];
  __shared__ float sbn[256];
  int t = threadIdx.x;
  if (t < NBOND * 32) bondS[t] = ((const float4*)bond)[t];
  if (t < 32) rootS[t] = ((const float4*)root)[t];
  sbn[t] = 0.0f;
  __syncthreads();

  int lane = t & 63;
  int laneq = lane & 31;   // feature quad owner
  int half = lane >> 5;    // which edge stream of the pair
  int wid = t >> 6;
  int gw = blockIdx.x * 4 + wid;
  int nw = gridDim.x * 4;
  const float4* hx4 = (const float4*)hx;
  float4* h24 = (float4*)h2;

  float s0 = 0.f, s1 = 0.f, s2 = 0.f, s3 = 0.f;
  float q0 = 0.f, q1 = 0.f, q2 = 0.f, q3 = 0.f;
  for (int n = gw; n < N_NODES; n += nw) {
    int e0 = csr_off[n], e1 = csr_off[n + 1];
    float a0 = 0.f, a1 = 0.f, a2 = 0.f, a3 = 0.f;
    int e = e0 + half;
    // unrolled 4x: edges e, e+2, e+4, e+6 for this half-wave
    for (; e + 6 < e1; e += 8) {
      int sp0 = src_pack[e];
      int sp1 = src_pack[e + 2];
      int sp2 = src_pack[e + 4];
      int sp3 = src_pack[e + 6];
      float nr0 = enorm[e];
      float nr1 = enorm[e + 2];
      float nr2 = enorm[e + 4];
      float nr3 = enorm[e + 6];
      float4 v0 = hx4[(size_t)(sp0 & 0xFFFFF) * 32 + laneq];
      float4 v1 = hx4[(size_t)(sp1 & 0xFFFFF) * 32 + laneq];
      float4 v2 = hx4[(size_t)(sp2 & 0xFFFFF) * 32 + laneq];
      float4 v3 = hx4[(size_t)(sp3 & 0xFFFFF) * 32 + laneq];
      float4 b0 = bondS[(sp0 >> 20) * 32 + laneq];
      float4 b1 = bondS[(sp1 >> 20) * 32 + laneq];
      float4 b2 = bondS[(sp2 >> 20) * 32 + laneq];
      float4 b3 = bondS[(sp3 >> 20) * 32 + laneq];
      a0 = fmaf(nr0, fmaxf(v0.x + b0.x, 0.f), a0);
      a1 = fmaf(nr0, fmaxf(v0.y + b0.y, 0.f), a1);
      a2 = fmaf(nr0, fmaxf(v0.z + b0.z, 0.f), a2);
      a3 = fmaf(nr0, fmaxf(v0.w + b0.w, 0.f), a3);
      a0 = fmaf(nr1, fmaxf(v1.x + b1.x, 0.f), a0);
      a1 = fmaf(nr1, fmaxf(v1.y + b1.y, 0.f), a1);
      a2 = fmaf(nr1, fmaxf(v1.z + b1.z, 0.f), a2);
      a3 = fmaf(nr1, fmaxf(v1.w + b1.w, 0.f), a3);
      a0 = fmaf(nr2, fmaxf(v2.x + b2.x, 0.f), a0);
      a1 = fmaf(nr2, fmaxf(v2.y + b2.y, 0.f), a1);
      a2 = fmaf(nr2, fmaxf(v2.z + b2.z, 0.f), a2);
      a3 = fmaf(nr2, fmaxf(v2.w + b2.w, 0.f), a3);
      a0 = fmaf(nr3, fmaxf(v3.x + b3.x, 0.f), a0);
      a1 = fmaf(nr3, fmaxf(v3.y + b3.y, 0.f), a1);
      a2 = fmaf(nr3, fmaxf(v3.z + b3.z, 0.f), a2);
      a3 = fmaf(nr3, fmaxf(v3.w + b3.w, 0.f), a3);
    }
    for (; e < e1; e += 2) {
      int sp = src_pack[e];
      float nrm = enorm[e];
      float4 v = hx4[(size_t)(sp & 0xFFFFF) * 32 + laneq];
      float4 eb = bondS[(sp >> 20) * 32 + laneq];
      a0 = fmaf(nrm, fmaxf(v.x + eb.x, 0.f), a0);
      a1 = fmaf(nrm, fmaxf(v.y + eb.y, 0.f), a1);
      a2 = fmaf(nrm, fmaxf(v.z + eb.z, 0.f), a2);
      a3 = fmaf(nrm, fmaxf(v.w + eb.w, 0.f), a3);
    }
    // combine the two halves (lane l and l^32 hold partials for same features)
    a0 += __shfl_xor(a0, 32, 64);
    a1 += __shfl_xor(a1, 32, 64);
    a2 += __shfl_xor(a2, 32, 64);
    a3 += __shfl_xor(a3, 32, 64);
    if (half == 0) {
      float inv = 1.0f / deg[n];
      float4 v = hx4[(size_t)n * 32 + laneq];
      float4 r = rootS[laneq];
      a0 += fmaxf(v.x + r.x, 0.f) * inv;
      a1 += fmaxf(v.y + r.y, 0.f) * inv;
      a2 += fmaxf(v.z + r.z, 0.f) * inv;
      a3 += fmaxf(v.w + r.w, 0.f) * inv;
      float4 o;
      o.x = a0; o.y = a1; o.z = a2; o.w = a3;
      h24[(size_t)n * 32 + laneq] = o;
      s0 += a0; s1 += a1; s2 += a2; s3 += a3;
      q0 += a0 * a0; q1 += a1 * a1; q2 += a2 * a2; q3 += a3 * a3;
    }
  }
  // block-level BN reduction: LDS atomics, then one global atomic per feature
  if (half == 0) {
    int f = 4 * laneq;
    atomicAdd(&sbn[f + 0], s0);
    atomicAdd(&sbn[f + 1], s1);
    atomicAdd(&sbn[f + 2], s2);
    atomicAdd(&sbn[f + 3], s3);
    atomicAdd(&sbn[128 + f + 0], q0);
    atomicAdd(&sbn[128 + f + 1], q1);
    atomicAdd(&sbn[128 + f + 2], q2);
    atomicAdd(&sbn[128 + f + 3], q3);
  }
  __syncthreads();
  atomicAdd(&bnbuf[t], sbn[t]);
}

// ---------------------------------------------------------------- BN finalize
__global__ __launch_bounds__(128) void bnfin_kernel(
    const float* __restrict__ bnbuf, const float* __restrict__ gamma,
    const float* __restrict__ beta, float* __restrict__ scale,
    float* __restrict__ shift) {
  int d = threadIdx.x;
  const float invN = 1.0f / (float)N_NODES;
  float mu = bnbuf[d] * invN;
  float ex2 = bnbuf[128 + d] * invN;
  float var = ex2 - mu * mu;
  float inv = rsqrtf(var + BN_EPS);
  float sc = gamma[d] * inv;
  scale[d] = sc;
  shift[d] = fmaf(-mu, sc, beta[d]);
}

// ---------------------------------------------------------------- pooling (batch is sorted)
__global__ __launch_bounds__(256) void pool_kernel(
    const float* __restrict__ h2, const int* __restrict__ batch,
    const float* __restrict__ scale, const float* __restrict__ shift,
    float* __restrict__ pool, float* __restrict__ pcnt) {
  int t = threadIdx.x;
  int lane = t & 63;
  int wid = t >> 6;
  int gw = blockIdx.x * 4 + wid;
  int nw = gridDim.x * 4;
  int chunk = (N_NODES + nw - 1) / nw;
  int n0 = gw * chunk;
  int n1 = min(n0 + chunk, N_NODES);
  if (n0 >= N_NODES) return;
  const float2* h22 = (const float2*)h2;
  int f0 = 2 * lane, f1 = f0 + 1;
  float sc0 = scale[f0], sc1 = scale[f1], sh0 = shift[f0], sh1 = shift[f1];
  int curg = batch[n0];
  float a0 = 0.f, a1 = 0.f, c = 0.f;
  for (int n = n0; n < n1; n++) {
    int g = batch[n];
    if (g != curg) {
      atomicAdd(&pool[curg * DIM + f0], a0);
      atomicAdd(&pool[curg * DIM + f1], a1);
      if (lane == 0) atomicAdd(&pcnt[curg], c);
      a0 = a1 = c = 0.f;
      curg = g;
    }
    float2 v = h22[(size_t)n * 64 + lane];
    a0 += fmaxf(fmaf(v.x, sc0, sh0), 0.f);
    a1 += fmaxf(fmaf(v.y, sc1, sh1), 0.f);
    c += 1.0f;
  }
  atomicAdd(&pool[curg * DIM + f0], a0);
  atomicAdd(&pool[curg * DIM + f1], a1);
  if (lane == 0) atomicAdd(&pcnt[curg], c);
}

// ---------------------------------------------------------------- output head
__global__ __launch_bounds__(256) void out_kernel(
    const float* __restrict__ pool, const float* __restrict__ pcnt,
    const float* __restrict__ Wout, const float* __restrict__ bout,
    float* __restrict__ out) {
  int idx = blockIdx.x * blockDim.x + threadIdx.x;
  if (idx >= NGRAPH * NTASK) return;
  int g = idx / NTASK, tt = idx % NTASK;
  float inv = 1.0f / fmaxf(pcnt[g], 1.0f);
  float acc = bout[tt];
  for (int d = 0; d < DIM; d++)
    acc = fmaf(pool[g * DIM + d] * inv, Wout[d * NTASK + tt], acc);
  out[idx] = acc;
}

// ----------------------------------------------------------------
extern "C" void kernel_launch(void* const* d_in, const int* in_sizes, int n_in,
                              void* d_out, int out_size, void* d_ws, size_t ws_size,
                              hipStream_t stream) {
  const float* x     = (const float*)d_in[0];
  const int*   eidx  = (const int*)d_in[1];
  const int*   row   = eidx;
  const int*   col   = eidx + N_EDGES;
  const int*   eattr = (const int*)d_in[2];
  const int*   batch = (const int*)d_in[3];
  const float* W     = (const float*)d_in[4];
  const float* b     = (const float*)d_in[5];
  const float* root  = (const float*)d_in[6];
  const float* bond  = (const float*)d_in[7];
  const float* gamma = (const float*)d_in[8];
  const float* beta  = (const float*)d_in[9];
  const float* Wout  = (const float*)d_in[10];
  const float* bout  = (const float*)d_in[11];
  float* out = (float*)d_out;

  // bump allocator over workspace (needs ~170 MB)
  char* w = (char*)d_ws;
  size_t off = 0;
  auto alloc = [&](size_t bytes) -> void* {
    void* p = w + off;
    off = (off + bytes + 511) & ~(size_t)511;
    return p;
  };
  // zero-init region (single memset): histograms, scatter positions, pool accumulators
  int*   cnt_row = (int*)alloc(N_NODES * 4);
  int*   cnt_col = (int*)alloc(N_NODES * 4);
  int*   pos     = (int*)alloc(N_NODES * 4);
  float* pool    = (float*)alloc(NGRAPH * DIM * 4);
  float* pcnt    = (float*)alloc(NGRAPH * 4);
  size_t zbytes  = off;
  // rest
  int*   csr     = (int*)alloc((N_NODES + 1) * 4);
  int*   bsum    = (int*)alloc(512 * 4);
  int*   bexcl   = (int*)alloc(512 * 4);
  float* deg     = (float*)alloc(N_NODES * 4);
  float* dinv    = (float*)alloc(N_NODES * 4);
  int*   spck    = (int*)alloc((size_t)N_EDGES * 4);
  float* enorm   = (float*)alloc((size_t)N_EDGES * 4);
  float* hx      = (float*)alloc((size_t)N_NODES * DIM * 4);
  float* hA      = (float*)alloc((size_t)N_NODES * DIM * 4);
  float* hB      = (float*)alloc((size_t)N_NODES * DIM * 4);
  float* bnbuf   = (float*)alloc(256 * 4);
  float* bnscale = (float*)alloc(DIM * 4);
  float* bnshift = (float*)alloc(DIM * 4);

  hipMemsetAsync(d_ws, 0, zbytes, stream);

  hist_kernel<<<2048, 256, 0, stream>>>(row, col, cnt_row, cnt_col);
  deg_kernel<<<(N_NODES + 255) / 256, 256, 0, stream>>>(cnt_row, deg, dinv);
  const int nb = (N_NODES + 255) / 256;  // 391
  scan1_kernel<<<nb, 256, 0, stream>>>(cnt_col, csr, bsum);
  scan2_kernel<<<1, 512, 0, stream>>>(bsum, bexcl, nb);
  scan3_kernel<<<nb, 256, 0, stream>>>(csr, bexcl);
  scatter_kernel<<<2048, 256, 0, stream>>>(row, col, eattr, csr, pos, dinv, spck, enorm);

  const int gblocks = (N_NODES + GBM - 1) / GBM;  // 782
  const float* hin = x;
  for (int l = 0; l < NLAYER; l++) {
    float* h2 = (l % 2 == 0) ? hA : hB;
    gemm_kernel<<<gblocks, 256, 0, stream>>>(
        hin, W + (size_t)l * DIM * DIM, b + l * DIM,
        bnscale, bnshift, (l > 0) ? 1 : 0, hx, bnbuf);
    agg_kernel<<<2048, 256, 0, stream>>>(
        hx, csr, spck, enorm, bond + (size_t)l * NBOND * DIM, root + l * DIM,
        deg, h2, bnbuf);
    bnfin_kernel<<<1, 128, 0, stream>>>(bnbuf, gamma + l * DIM, beta + l * DIM,
                                        bnscale, bnshift);
    hin = h2;
  }
  pool_kernel<<<256, 256, 0, stream>>>(hin, batch, bnscale, bnshift, pool, pcnt);
  out_kernel<<<5, 256, 0, stream>>>(pool, pcnt, Wout, bout, out);
}

// Round 4
// 5854.280 us; speedup vs baseline: 1.3367x; 1.3367x over previous
//
#include <hip/hip_runtime.h>
#include <math.h>

#define N_NODES 100000
#define N_EDGES 1600000
#define DIM     128
#define NLAYER  5
#define NGRAPH  128
#define NTASK   10
#define NBOND   4
#define BN_EPS  1e-5f

// ---------------------------------------------------------------- histograms
__global__ __launch_bounds__(256) void hist_kernel(
    const int* __restrict__ row, const int* __restrict__ col,
    int* __restrict__ cnt_row, int* __restrict__ cnt_col) {
  int i = blockIdx.x * blockDim.x + threadIdx.x;
  int stride = gridDim.x * blockDim.x;
  for (; i < N_EDGES; i += stride) {
    atomicAdd(&cnt_row[row[i]], 1);
    atomicAdd(&cnt_col[col[i]], 1);
  }
}

__global__ __launch_bounds__(256) void deg_kernel(
    const int* __restrict__ cnt_row, float* __restrict__ deg, float* __restrict__ dinv) {
  int i = blockIdx.x * blockDim.x + threadIdx.x;
  if (i < N_NODES) {
    float d = (float)cnt_row[i] + 1.0f;
    deg[i] = d;
    dinv[i] = rsqrtf(d);
  }
}

// ---------------------------------------------------------------- scan (CSR offsets)
__global__ __launch_bounds__(256) void scan1_kernel(
    const int* __restrict__ cnt, int* __restrict__ excl, int* __restrict__ bsum) {
  __shared__ int s[256];
  int t = threadIdx.x;
  int i = blockIdx.x * 256 + t;
  int v = (i < N_NODES) ? cnt[i] : 0;
  s[t] = v;
  __syncthreads();
  for (int off = 1; off < 256; off <<= 1) {
    int add = (t >= off) ? s[t - off] : 0;
    __syncthreads();
    s[t] += add;
    __syncthreads();
  }
  if (i < N_NODES) excl[i] = s[t] - v;   // exclusive within block
  if (t == 255) bsum[blockIdx.x] = s[255];
}

__global__ __launch_bounds__(512) void scan2_kernel(
    const int* __restrict__ bsum, int* __restrict__ bexcl, int nb) {
  __shared__ int s[512];
  int t = threadIdx.x;
  int v = (t < nb) ? bsum[t] : 0;
  s[t] = v;
  __syncthreads();
  for (int off = 1; off < 512; off <<= 1) {
    int add = (t >= off) ? s[t - off] : 0;
    __syncthreads();
    s[t] += add;
    __syncthreads();
  }
  if (t < nb) bexcl[t] = s[t] - v;
}

__global__ __launch_bounds__(256) void scan3_kernel(
    int* __restrict__ excl, const int* __restrict__ bexcl) {
  int i = blockIdx.x * 256 + threadIdx.x;
  if (i < N_NODES) excl[i] += bexcl[blockIdx.x];
  if (i == 0) excl[N_NODES] = N_EDGES;
}

// ---------------------------------------------------------------- CSR scatter
__global__ __launch_bounds__(256) void scatter_kernel(
    const int* __restrict__ row, const int* __restrict__ col,
    const int* __restrict__ attr, const int* __restrict__ csr_off,
    int* __restrict__ pos, const float* __restrict__ dinv,
    int* __restrict__ src_pack, float* __restrict__ enorm) {
  int e = blockIdx.x * blockDim.x + threadIdx.x;
  int stride = gridDim.x * blockDim.x;
  for (; e < N_EDGES; e += stride) {
    int d = col[e];
    int s = row[e];
    int p = csr_off[d] + atomicAdd(&pos[d], 1);
    src_pack[p] = s | (attr[e] << 20);         // src < 2^20, attr < 4
    enorm[p] = dinv[s] * dinv[d];
  }
}

// ---------------------------------------------------------------- GEMM: hx = act(hin) @ W + b
// 2D register-tiled LDS GEMM, register-liveness-disciplined (R3 spilled at
// VGPR=128 cap -> 3.6 GB scratch traffic; R4 removes the cross-phase register
// prefetch and streams h fragments one at a time).
// Block = 256 threads -> 128x128 output tile; K in two 64-wide phases.
// LDS 64 KB (hs swizzled + Ws) -> 2 blocks/CU. Per-thread 8x8 tile:
// 16 ds_read_b128 per 256 FMAs. Peak live regs ~115 (acc 64 + w 32 + hf 4).
// BN+relu of previous layer fused into h staging. FMA order: init=bias,
// k ascending -> bit-identical.
#define GBM 128
__global__ __launch_bounds__(256) void gemm_kernel(
    const float* __restrict__ hin, const float* __restrict__ W,
    const float* __restrict__ bias, const float* __restrict__ scale,
    const float* __restrict__ shift, int useact,
    float* __restrict__ hx, float* __restrict__ bnzero) {
  __shared__ float4 lds[4096];          // [0..2047]=hs, [2048..4095]=Ws
  float4* hs = lds;
  float4* Ws = lds + 2048;
  int t = threadIdx.x;
  if (blockIdx.x == 0) bnzero[t] = 0.0f;  // zero BN accumulators (256 floats)
  int cg = t & 15;                      // column group: cols 4cg.. and 64+4cg..
  int rg = t >> 4;                      // row group: rows rg, rg+16, ..., rg+112
  int cr = rg & 3;                      // hs swizzle constant for this thread
  int r0 = blockIdx.x * GBM;
  if (r0 > N_NODES - GBM) r0 = N_NODES - GBM;   // tail overlap (benign dup stores)

  // act params for this thread's staged k-slot (slot = t&15 = cg, constant)
  float scA[4], shA[4], scB[4], shB[4];
  if (useact) {
    int kb = cg * 4;
#pragma unroll
    for (int j = 0; j < 4; j++) {
      scA[j] = scale[kb + j];       shA[j] = shift[kb + j];
      scB[j] = scale[64 + kb + j];  shB[j] = shift[64 + kb + j];
    }
  }

  const float4* hg = (const float4*)hin;
  const float4* wg = (const float4*)W;

  float acc0[8][4], acc1[8][4];
  {
    float b0[4], b1[4];
#pragma unroll
    for (int j = 0; j < 4; j++) {
      b0[j] = bias[4 * cg + j];
      b1[j] = bias[64 + 4 * cg + j];
    }
#pragma unroll
    for (int i = 0; i < 8; i++)
#pragma unroll
      for (int j = 0; j < 4; j++) { acc0[i][j] = b0[j]; acc1[i][j] = b1[j]; }
  }

  // ---- phase A: stage LDS (transient regs only)
#pragma unroll
  for (int it = 0; it < 8; it++) {
    int u = t + it * 256;
    int lrow = u >> 4, s = u & 15;
    float4 v = hg[(size_t)(r0 + lrow) * 32 + s];
    if (useact) {
      v.x = fmaxf(fmaf(v.x, scA[0], shA[0]), 0.f);
      v.y = fmaxf(fmaf(v.y, scA[1], shA[1]), 0.f);
      v.z = fmaxf(fmaf(v.z, scA[2], shA[2]), 0.f);
      v.w = fmaxf(fmaf(v.w, scA[3], shA[3]), 0.f);
    }
    hs[lrow * 16 + (s ^ (lrow & 3))] = v;
    Ws[u] = wg[u];                      // W rows 0..63
  }
  __syncthreads();
  // ---- compute k = 0..63
#pragma unroll
  for (int k4 = 0; k4 < 16; k4++) {
    float4 w0[4], w1[4];
#pragma unroll
    for (int kk = 0; kk < 4; kk++) {
      w0[kk] = Ws[(k4 * 4 + kk) * 32 + cg];
      w1[kk] = Ws[(k4 * 4 + kk) * 32 + 16 + cg];
    }
    int soff = k4 ^ cr;
#pragma unroll
    for (int i = 0; i < 8; i++) {
      float4 hf = hs[(rg + 16 * i) * 16 + soff];
#pragma unroll
      for (int kk = 0; kk < 4; kk++) {
        float hv = ((const float*)&hf)[kk];
        acc0[i][0] = fmaf(hv, w0[kk].x, acc0[i][0]);
        acc0[i][1] = fmaf(hv, w0[kk].y, acc0[i][1]);
        acc0[i][2] = fmaf(hv, w0[kk].z, acc0[i][2]);
        acc0[i][3] = fmaf(hv, w0[kk].w, acc0[i][3]);
        acc1[i][0] = fmaf(hv, w1[kk].x, acc1[i][0]);
        acc1[i][1] = fmaf(hv, w1[kk].y, acc1[i][1]);
        acc1[i][2] = fmaf(hv, w1[kk].z, acc1[i][2]);
        acc1[i][3] = fmaf(hv, w1[kk].w, acc1[i][3]);
      }
    }
  }
  __syncthreads();
  // ---- phase B: stage LDS
#pragma unroll
  for (int it = 0; it < 8; it++) {
    int u = t + it * 256;
    int lrow = u >> 4, s = u & 15;
    float4 v = hg[(size_t)(r0 + lrow) * 32 + 16 + s];
    if (useact) {
      v.x = fmaxf(fmaf(v.x, scB[0], shB[0]), 0.f);
      v.y = fmaxf(fmaf(v.y, scB[1], shB[1]), 0.f);
      v.z = fmaxf(fmaf(v.z, scB[2], shB[2]), 0.f);
      v.w = fmaxf(fmaf(v.w, scB[3], shB[3]), 0.f);
    }
    hs[lrow * 16 + (s ^ (lrow & 3))] = v;
    Ws[u] = wg[64 * 32 + u];            // W rows 64..127
  }
  __syncthreads();
  // ---- compute k = 64..127
#pragma unroll
  for (int k4 = 0; k4 < 16; k4++) {
    float4 w0[4], w1[4];
#pragma unroll
    for (int kk = 0; kk < 4; kk++) {
      w0[kk] = Ws[(k4 * 4 + kk) * 32 + cg];
      w1[kk] = Ws[(k4 * 4 + kk) * 32 + 16 + cg];
    }
    int soff = k4 ^ cr;
#pragma unroll
    for (int i = 0; i < 8; i++) {
      float4 hf = hs[(rg + 16 * i) * 16 + soff];
#pragma unroll
      for (int kk = 0; kk < 4; kk++) {
        float hv = ((const float*)&hf)[kk];
        acc0[i][0] = fmaf(hv, w0[kk].x, acc0[i][0]);
        acc0[i][1] = fmaf(hv, w0[kk].y, acc0[i][1]);
        acc0[i][2] = fmaf(hv, w0[kk].z, acc0[i][2]);
        acc0[i][3] = fmaf(hv, w0[kk].w, acc0[i][3]);
        acc1[i][0] = fmaf(hv, w1[kk].x, acc1[i][0]);
        acc1[i][1] = fmaf(hv, w1[kk].y, acc1[i][1]);
        acc1[i][2] = fmaf(hv, w1[kk].z, acc1[i][2]);
        acc1[i][3] = fmaf(hv, w1[kk].w, acc1[i][3]);
      }
    }
  }
  // ---- store
  float4* ox = (float4*)hx;
#pragma unroll
  for (int i = 0; i < 8; i++) {
    int grow = r0 + rg + 16 * i;
    float4 s0, s1;
    s0.x = acc0[i][0]; s0.y = acc0[i][1]; s0.z = acc0[i][2]; s0.w = acc0[i][3];
    s1.x = acc1[i][0]; s1.y = acc1[i][1]; s1.z = acc1[i][2]; s1.w = acc1[i][3];
    ox[(size_t)grow * 32 + cg] = s0;
    ox[(size_t)grow * 32 + 16 + cg] = s1;
  }
}

// ---------------------------------------------------------------- edge aggregation
// One wave per destination node; lane&31 owns features [4q..4q+3] via float4.
// Two 32-lane halves process two edge streams; each half unrolled 4x ->
// 8 independent 512B row gathers in flight per wave. Halves combined via
// shfl_xor(32). BN partials: LDS block reduce -> one global atomic/feature.
__global__ __launch_bounds__(256) void agg_kernel(
    const float* __restrict__ hx, const int* __restrict__ csr_off,
    const int* __restrict__ src_pack, const float* __restrict__ enorm,
    const float* __restrict__ bond, const float* __restrict__ root,
    const float* __restrict__ deg, float* __restrict__ h2,
    float* __restrict__ bnbuf) {
  __shared__ float4 bondS[NBOND * 32];
  __shared__ float4 rootS[32];
  __shared__ float sbn[256];
  int t = threadIdx.x;
  if (t < NBOND * 32) bondS[t] = ((const float4*)bond)[t];
  if (t < 32) rootS[t] = ((const float4*)root)[t];
  sbn[t] = 0.0f;
  __syncthreads();

  int lane = t & 63;
  int laneq = lane & 31;   // feature quad owner
  int half = lane >> 5;    // which edge stream of the pair
  int wid = t >> 6;
  int gw = blockIdx.x * 4 + wid;
  int nw = gridDim.x * 4;
  const float4* hx4 = (const float4*)hx;
  float4* h24 = (float4*)h2;

  float s0 = 0.f, s1 = 0.f, s2 = 0.f, s3 = 0.f;
  float q0 = 0.f, q1 = 0.f, q2 = 0.f, q3 = 0.f;
  for (int n = gw; n < N_NODES; n += nw) {
    int e0 = csr_off[n], e1 = csr_off[n + 1];
    float a0 = 0.f, a1 = 0.f, a2 = 0.f, a3 = 0.f;
    int e = e0 + half;
    // unrolled 4x: edges e, e+2, e+4, e+6 for this half-wave
    for (; e + 6 < e1; e += 8) {
      int sp0 = src_pack[e];
      int sp1 = src_pack[e + 2];
      int sp2 = src_pack[e + 4];
      int sp3 = src_pack[e + 6];
      float nr0 = enorm[e];
      float nr1 = enorm[e + 2];
      float nr2 = enorm[e + 4];
      float nr3 = enorm[e + 6];
      float4 v0 = hx4[(size_t)(sp0 & 0xFFFFF) * 32 + laneq];
      float4 v1 = hx4[(size_t)(sp1 & 0xFFFFF) * 32 + laneq];
      float4 v2 = hx4[(size_t)(sp2 & 0xFFFFF) * 32 + laneq];
      float4 v3 = hx4[(size_t)(sp3 & 0xFFFFF) * 32 + laneq];
      float4 b0 = bondS[(sp0 >> 20) * 32 + laneq];
      float4 b1 = bondS[(sp1 >> 20) * 32 + laneq];
      float4 b2 = bondS[(sp2 >> 20) * 32 + laneq];
      float4 b3 = bondS[(sp3 >> 20) * 32 + laneq];
      a0 = fmaf(nr0, fmaxf(v0.x + b0.x, 0.f), a0);
      a1 = fmaf(nr0, fmaxf(v0.y + b0.y, 0.f), a1);
      a2 = fmaf(nr0, fmaxf(v0.z + b0.z, 0.f), a2);
      a3 = fmaf(nr0, fmaxf(v0.w + b0.w, 0.f), a3);
      a0 = fmaf(nr1, fmaxf(v1.x + b1.x, 0.f), a0);
      a1 = fmaf(nr1, fmaxf(v1.y + b1.y, 0.f), a1);
      a2 = fmaf(nr1, fmaxf(v1.z + b1.z, 0.f), a2);
      a3 = fmaf(nr1, fmaxf(v1.w + b1.w, 0.f), a3);
      a0 = fmaf(nr2, fmaxf(v2.x + b2.x, 0.f), a0);
      a1 = fmaf(nr2, fmaxf(v2.y + b2.y, 0.f), a1);
      a2 = fmaf(nr2, fmaxf(v2.z + b2.z, 0.f), a2);
      a3 = fmaf(nr2, fmaxf(v2.w + b2.w, 0.f), a3);
      a0 = fmaf(nr3, fmaxf(v3.x + b3.x, 0.f), a0);
      a1 = fmaf(nr3, fmaxf(v3.y + b3.y, 0.f), a1);
      a2 = fmaf(nr3, fmaxf(v3.z + b3.z, 0.f), a2);
      a3 = fmaf(nr3, fmaxf(v3.w + b3.w, 0.f), a3);
    }
    for (; e < e1; e += 2) {
      int sp = src_pack[e];
      float nrm = enorm[e];
      float4 v = hx4[(size_t)(sp & 0xFFFFF) * 32 + laneq];
      float4 eb = bondS[(sp >> 20) * 32 + laneq];
      a0 = fmaf(nrm, fmaxf(v.x + eb.x, 0.f), a0);
      a1 = fmaf(nrm, fmaxf(v.y + eb.y, 0.f), a1);
      a2 = fmaf(nrm, fmaxf(v.z + eb.z, 0.f), a2);
      a3 = fmaf(nrm, fmaxf(v.w + eb.w, 0.f), a3);
    }
    // combine the two halves (lane l and l^32 hold partials for same features)
    a0 += __shfl_xor(a0, 32, 64);
    a1 += __shfl_xor(a1, 32, 64);
    a2 += __shfl_xor(a2, 32, 64);
    a3 += __shfl_xor(a3, 32, 64);
    if (half == 0) {
      float inv = 1.0f / deg[n];
      float4 v = hx4[(size_t)n * 32 + laneq];
      float4 r = rootS[laneq];
      a0 += fmaxf(v.x + r.x, 0.f) * inv;
      a1 += fmaxf(v.y + r.y, 0.f) * inv;
      a2 += fmaxf(v.z + r.z, 0.f) * inv;
      a3 += fmaxf(v.w + r.w, 0.f) * inv;
      float4 o;
      o.x = a0; o.y = a1; o.z = a2; o.w = a3;
      h24[(size_t)n * 32 + laneq] = o;
      s0 += a0; s1 += a1; s2 += a2; s3 += a3;
      q0 += a0 * a0; q1 += a1 * a1; q2 += a2 * a2; q3 += a3 * a3;
    }
  }
  // block-level BN reduction: LDS atomics, then one global atomic per feature
  if (half == 0) {
    int f = 4 * laneq;
    atomicAdd(&sbn[f + 0], s0);
    atomicAdd(&sbn[f + 1], s1);
    atomicAdd(&sbn[f + 2], s2);
    atomicAdd(&sbn[f + 3], s3);
    atomicAdd(&sbn[128 + f + 0], q0);
    atomicAdd(&sbn[128 + f + 1], q1);
    atomicAdd(&sbn[128 + f + 2], q2);
    atomicAdd(&sbn[128 + f + 3], q3);
  }
  __syncthreads();
  atomicAdd(&bnbuf[t], sbn[t]);
}

// ---------------------------------------------------------------- BN finalize
__global__ __launch_bounds__(128) void bnfin_kernel(
    const float* __restrict__ bnbuf, const float* __restrict__ gamma,
    const float* __restrict__ beta, float* __restrict__ scale,
    float* __restrict__ shift) {
  int d = threadIdx.x;
  const float invN = 1.0f / (float)N_NODES;
  float mu = bnbuf[d] * invN;
  float ex2 = bnbuf[128 + d] * invN;
  float var = ex2 - mu * mu;
  float inv = rsqrtf(var + BN_EPS);
  float sc = gamma[d] * inv;
  scale[d] = sc;
  shift[d] = fmaf(-mu, sc, beta[d]);
}

// ---------------------------------------------------------------- pooling (batch is sorted)
__global__ __launch_bounds__(256) void pool_kernel(
    const float* __restrict__ h2, const int* __restrict__ batch,
    const float* __restrict__ scale, const float* __restrict__ shift,
    float* __restrict__ pool, float* __restrict__ pcnt) {
  int t = threadIdx.x;
  int lane = t & 63;
  int wid = t >> 6;
  int gw = blockIdx.x * 4 + wid;
  int nw = gridDim.x * 4;
  int chunk = (N_NODES + nw - 1) / nw;
  int n0 = gw * chunk;
  int n1 = min(n0 + chunk, N_NODES);
  if (n0 >= N_NODES) return;
  const float2* h22 = (const float2*)h2;
  int f0 = 2 * lane, f1 = f0 + 1;
  float sc0 = scale[f0], sc1 = scale[f1], sh0 = shift[f0], sh1 = shift[f1];
  int curg = batch[n0];
  float a0 = 0.f, a1 = 0.f, c = 0.f;
  for (int n = n0; n < n1; n++) {
    int g = batch[n];
    if (g != curg) {
      atomicAdd(&pool[curg * DIM + f0], a0);
      atomicAdd(&pool[curg * DIM + f1], a1);
      if (lane == 0) atomicAdd(&pcnt[curg], c);
      a0 = a1 = c = 0.f;
      curg = g;
    }
    float2 v = h22[(size_t)n * 64 + lane];
    a0 += fmaxf(fmaf(v.x, sc0, sh0), 0.f);
    a1 += fmaxf(fmaf(v.y, sc1, sh1), 0.f);
    c += 1.0f;
  }
  atomicAdd(&pool[curg * DIM + f0], a0);
  atomicAdd(&pool[curg * DIM + f1], a1);
  if (lane == 0) atomicAdd(&pcnt[curg], c);
}

// ---------------------------------------------------------------- output head
__global__ __launch_bounds__(256) void out_kernel(
    const float* __restrict__ pool, const float* __restrict__ pcnt,
    const float* __restrict__ Wout, const float* __restrict__ bout,
    float* __restrict__ out) {
  int idx = blockIdx.x * blockDim.x + threadIdx.x;
  if (idx >= NGRAPH * NTASK) return;
  int g = idx / NTASK, tt = idx % NTASK;
  float inv = 1.0f / fmaxf(pcnt[g], 1.0f);
  float acc = bout[tt];
  for (int d = 0; d < DIM; d++)
    acc = fmaf(pool[g * DIM + d] * inv, Wout[d * NTASK + tt], acc);
  out[idx] = acc;
}

// ----------------------------------------------------------------
extern "C" void kernel_launch(void* const* d_in, const int* in_sizes, int n_in,
                              void* d_out, int out_size, void* d_ws, size_t ws_size,
                              hipStream_t stream) {
  const float* x     = (const float*)d_in[0];
  const int*   eidx  = (const int*)d_in[1];
  const int*   row   = eidx;
  const int*   col   = eidx + N_EDGES;
  const int*   eattr = (const int*)d_in[2];
  const int*   batch = (const int*)d_in[3];
  const float* W     = (const float*)d_in[4];
  const float* b     = (const float*)d_in[5];
  const float* root  = (const float*)d_in[6];
  const float* bond  = (const float*)d_in[7];
  const float* gamma = (const float*)d_in[8];
  const float* beta  = (const float*)d_in[9];
  const float* Wout  = (const float*)d_in[10];
  const float* bout  = (const float*)d_in[11];
  float* out = (float*)d_out;

  // bump allocator over workspace (needs ~170 MB)
  char* w = (char*)d_ws;
  size_t off = 0;
  auto alloc = [&](size_t bytes) -> void* {
    void* p = w + off;
    off = (off + bytes + 511) & ~(size_t)511;
    return p;
  };
  // zero-init region (single memset): histograms, scatter positions, pool accumulators
  int*   cnt_row = (int*)alloc(N_NODES * 4);
  int*   cnt_col = (int*)alloc(N_NODES * 4);
  int*   pos     = (int*)alloc(N_NODES * 4);
  float* pool    = (float*)alloc(NGRAPH * DIM * 4);
  float* pcnt    = (float*)alloc(NGRAPH * 4);
  size_t zbytes  = off;
  // rest
  int*   csr     = (int*)alloc((N_NODES + 1) * 4);
  int*   bsum    = (int*)alloc(512 * 4);
  int*   bexcl   = (int*)alloc(512 * 4);
  float* deg     = (float*)alloc(N_NODES * 4);
  float* dinv    = (float*)alloc(N_NODES * 4);
  int*   spck    = (int*)alloc((size_t)N_EDGES * 4);
  float* enorm   = (float*)alloc((size_t)N_EDGES * 4);
  float* hx      = (float*)alloc((size_t)N_NODES * DIM * 4);
  float* hA      = (float*)alloc((size_t)N_NODES * DIM * 4);
  float* hB      = (float*)alloc((size_t)N_NODES * DIM * 4);
  float* bnbuf   = (float*)alloc(256 * 4);
  float* bnscale = (float*)alloc(DIM * 4);
  float* bnshift = (float*)alloc(DIM * 4);

  hipMemsetAsync(d_ws, 0, zbytes, stream);

  hist_kernel<<<2048, 256, 0, stream>>>(row, col, cnt_row, cnt_col);
  deg_kernel<<<(N_NODES + 255) / 256, 256, 0, stream>>>(cnt_row, deg, dinv);
  const int nb = (N_NODES + 255) / 256;  // 391
  scan1_kernel<<<nb, 256, 0, stream>>>(cnt_col, csr, bsum);
  scan2_kernel<<<1, 512, 0, stream>>>(bsum, bexcl, nb);
  scan3_kernel<<<nb, 256, 0, stream>>>(csr, bexcl);
  scatter_kernel<<<2048, 256, 0, stream>>>(row, col, eattr, csr, pos, dinv, spck, enorm);

  const int gblocks = (N_NODES + GBM - 1) / GBM;  // 782
  const float* hin = x;
  for (int l = 0; l < NLAYER; l++) {
    float* h2 = (l % 2 == 0) ? hA : hB;
    gemm_kernel<<<gblocks, 256, 0, stream>>>(
        hin, W + (size_t)l * DIM * DIM, b + l * DIM,
        bnscale, bnshift, (l > 0) ? 1 : 0, hx, bnbuf);
    agg_kernel<<<2048, 256, 0, stream>>>(
        hx, csr, spck, enorm, bond + (size_t)l * NBOND * DIM, root + l * DIM,
        deg, h2, bnbuf);
    bnfin_kernel<<<1, 128, 0, stream>>>(bnbuf, gamma + l * DIM, beta + l * DIM,
                                        bnscale, bnshift);
    hin = h2;
  }
  pool_kernel<<<256, 256, 0, stream>>>(hin, batch, bnscale, bnshift, pool, pcnt);
  out_kernel<<<5, 256, 0, stream>>>(pool, pcnt, Wout, bout, out);
}

// Round 5
// 1490.231 us; speedup vs baseline: 5.2511x; 3.9284x over previous
//
#include <hip/hip_runtime.h>
#include <math.h>

#define N_NODES 100000
#define N_EDGES 1600000
#define DIM     128
#define NLAYER  5
#define NGRAPH  128
#define NTASK   10
#define NBOND   4
#define BN_EPS  1e-5f

// ---------------------------------------------------------------- histograms
__global__ __launch_bounds__(256) void hist_kernel(
    const int* __restrict__ row, const int* __restrict__ col,
    int* __restrict__ cnt_row, int* __restrict__ cnt_col) {
  int i = blockIdx.x * blockDim.x + threadIdx.x;
  int stride = gridDim.x * blockDim.x;
  for (; i < N_EDGES; i += stride) {
    atomicAdd(&cnt_row[row[i]], 1);
    atomicAdd(&cnt_col[col[i]], 1);
  }
}

__global__ __launch_bounds__(256) void deg_kernel(
    const int* __restrict__ cnt_row, float* __restrict__ deg, float* __restrict__ dinv) {
  int i = blockIdx.x * blockDim.x + threadIdx.x;
  if (i < N_NODES) {
    float d = (float)cnt_row[i] + 1.0f;
    deg[i] = d;
    dinv[i] = rsqrtf(d);
  }
}

// ---------------------------------------------------------------- scan (CSR offsets)
__global__ __launch_bounds__(256) void scan1_kernel(
    const int* __restrict__ cnt, int* __restrict__ excl, int* __restrict__ bsum) {
  __shared__ int s[256];
  int t = threadIdx.x;
  int i = blockIdx.x * 256 + t;
  int v = (i < N_NODES) ? cnt[i] : 0;
  s[t] = v;
  __syncthreads();
  for (int off = 1; off < 256; off <<= 1) {
    int add = (t >= off) ? s[t - off] : 0;
    __syncthreads();
    s[t] += add;
    __syncthreads();
  }
  if (i < N_NODES) excl[i] = s[t] - v;   // exclusive within block
  if (t == 255) bsum[blockIdx.x] = s[255];
}

__global__ __launch_bounds__(512) void scan2_kernel(
    const int* __restrict__ bsum, int* __restrict__ bexcl, int nb) {
  __shared__ int s[512];
  int t = threadIdx.x;
  int v = (t < nb) ? bsum[t] : 0;
  s[t] = v;
  __syncthreads();
  for (int off = 1; off < 512; off <<= 1) {
    int add = (t >= off) ? s[t - off] : 0;
    __syncthreads();
    s[t] += add;
    __syncthreads();
  }
  if (t < nb) bexcl[t] = s[t] - v;
}

__global__ __launch_bounds__(256) void scan3_kernel(
    int* __restrict__ excl, const int* __restrict__ bexcl) {
  int i = blockIdx.x * 256 + threadIdx.x;
  if (i < N_NODES) excl[i] += bexcl[blockIdx.x];
  if (i == 0) excl[N_NODES] = N_EDGES;
}

// ---------------------------------------------------------------- CSR scatter
__global__ __launch_bounds__(256) void scatter_kernel(
    const int* __restrict__ row, const int* __restrict__ col,
    const int* __restrict__ attr, const int* __restrict__ csr_off,
    int* __restrict__ pos, const float* __restrict__ dinv,
    int* __restrict__ src_pack, float* __restrict__ enorm) {
  int e = blockIdx.x * blockDim.x + threadIdx.x;
  int stride = gridDim.x * blockDim.x;
  for (; e < N_EDGES; e += stride) {
    int d = col[e];
    int s = row[e];
    int p = csr_off[d] + atomicAdd(&pos[d], 1);
    src_pack[p] = s | (attr[e] << 20);         // src < 2^20, attr < 4
    enorm[p] = dinv[s] * dinv[d];
  }
}

// ---------------------------------------------------------------- GEMM: hx = act(hin) @ W + b
// 2D register-tiled LDS GEMM. R3/R4 lesson: FULL UNROLL of the k4 loop
// (4096-FMA body) let the scheduler hoist ds_read results -> live-range
// explosion -> spill (VGPR=256 cap, ~800 MB scratch writes/dispatch).
// R5: k4 loops ROLLED (#pragma unroll 1) -> per-iter live set bounded:
// acc 64 + w 32 + hf 4 + act 16 + addr ~= 150 VGPR, no spill.
// Block = 256 threads -> 128x128 tile; K in two 64-wide phases; LDS 64 KB
// (hs swizzled by row&3 + Ws) -> 2 blocks/CU. Per-thread 8x8 tile:
// 16 ds_read_b128 per 256 FMAs per k4 (VALU-bound ratio).
// BN+relu fused into h staging. FMA order: init=bias, k ascending.
#define GBM 128
__global__ __launch_bounds__(256) void gemm_kernel(
    const float* __restrict__ hin, const float* __restrict__ W,
    const float* __restrict__ bias, const float* __restrict__ scale,
    const float* __restrict__ shift, int useact,
    float* __restrict__ hx, float* __restrict__ bnzero) {
  __shared__ float4 lds[4096];          // [0..2047]=hs, [2048..4095]=Ws
  float4* hs = lds;
  float4* Ws = lds + 2048;
  int t = threadIdx.x;
  if (blockIdx.x == 0) bnzero[t] = 0.0f;  // zero BN accumulators (256 floats)
  int cg = t & 15;                      // column group: cols 4cg.. and 64+4cg..
  int rg = t >> 4;                      // row group: rows rg, rg+16, ..., rg+112
  int cr = rg & 3;                      // hs swizzle constant for this thread
  int r0 = blockIdx.x * GBM;
  if (r0 > N_NODES - GBM) r0 = N_NODES - GBM;   // tail overlap (benign dup stores)

  // act params for this thread's staged k-slot (slot = t&15 = cg, constant)
  float scA[4], shA[4], scB[4], shB[4];
  if (useact) {
    int kb = cg * 4;
#pragma unroll
    for (int j = 0; j < 4; j++) {
      scA[j] = scale[kb + j];       shA[j] = shift[kb + j];
      scB[j] = scale[64 + kb + j];  shB[j] = shift[64 + kb + j];
    }
  }

  const float4* hg = (const float4*)hin;
  const float4* wg = (const float4*)W;

  float acc0[8][4], acc1[8][4];
  {
    float b0[4], b1[4];
#pragma unroll
    for (int j = 0; j < 4; j++) {
      b0[j] = bias[4 * cg + j];
      b1[j] = bias[64 + 4 * cg + j];
    }
#pragma unroll
    for (int i = 0; i < 8; i++)
#pragma unroll
      for (int j = 0; j < 4; j++) { acc0[i][j] = b0[j]; acc1[i][j] = b1[j]; }
  }

  // ---- phase A: stage LDS (transient regs only)
#pragma unroll
  for (int it = 0; it < 8; it++) {
    int u = t + it * 256;
    int lrow = u >> 4, s = u & 15;
    float4 v = hg[(size_t)(r0 + lrow) * 32 + s];
    if (useact) {
      v.x = fmaxf(fmaf(v.x, scA[0], shA[0]), 0.f);
      v.y = fmaxf(fmaf(v.y, scA[1], shA[1]), 0.f);
      v.z = fmaxf(fmaf(v.z, scA[2], shA[2]), 0.f);
      v.w = fmaxf(fmaf(v.w, scA[3], shA[3]), 0.f);
    }
    hs[lrow * 16 + (s ^ (lrow & 3))] = v;
    Ws[u] = wg[u];                      // W rows 0..63
  }
  __syncthreads();
  // ---- compute k = 0..63 (ROLLED: bounded live ranges)
#pragma unroll 1
  for (int k4 = 0; k4 < 16; k4++) {
    float4 w0[4], w1[4];
#pragma unroll
    for (int kk = 0; kk < 4; kk++) {
      w0[kk] = Ws[(k4 * 4 + kk) * 32 + cg];
      w1[kk] = Ws[(k4 * 4 + kk) * 32 + 16 + cg];
    }
    int soff = k4 ^ cr;
#pragma unroll
    for (int i = 0; i < 8; i++) {
      float4 hf = hs[(rg + 16 * i) * 16 + soff];
#pragma unroll
      for (int kk = 0; kk < 4; kk++) {
        float hv = ((const float*)&hf)[kk];
        acc0[i][0] = fmaf(hv, w0[kk].x, acc0[i][0]);
        acc0[i][1] = fmaf(hv, w0[kk].y, acc0[i][1]);
        acc0[i][2] = fmaf(hv, w0[kk].z, acc0[i][2]);
        acc0[i][3] = fmaf(hv, w0[kk].w, acc0[i][3]);
        acc1[i][0] = fmaf(hv, w1[kk].x, acc1[i][0]);
        acc1[i][1] = fmaf(hv, w1[kk].y, acc1[i][1]);
        acc1[i][2] = fmaf(hv, w1[kk].z, acc1[i][2]);
        acc1[i][3] = fmaf(hv, w1[kk].w, acc1[i][3]);
      }
    }
  }
  __syncthreads();
  // ---- phase B: stage LDS
#pragma unroll
  for (int it = 0; it < 8; it++) {
    int u = t + it * 256;
    int lrow = u >> 4, s = u & 15;
    float4 v = hg[(size_t)(r0 + lrow) * 32 + 16 + s];
    if (useact) {
      v.x = fmaxf(fmaf(v.x, scB[0], shB[0]), 0.f);
      v.y = fmaxf(fmaf(v.y, scB[1], shB[1]), 0.f);
      v.z = fmaxf(fmaf(v.z, scB[2], shB[2]), 0.f);
      v.w = fmaxf(fmaf(v.w, scB[3], shB[3]), 0.f);
    }
    hs[lrow * 16 + (s ^ (lrow & 3))] = v;
    Ws[u] = wg[64 * 32 + u];            // W rows 64..127
  }
  __syncthreads();
  // ---- compute k = 64..127 (ROLLED)
#pragma unroll 1
  for (int k4 = 0; k4 < 16; k4++) {
    float4 w0[4], w1[4];
#pragma unroll
    for (int kk = 0; kk < 4; kk++) {
      w0[kk] = Ws[(k4 * 4 + kk) * 32 + cg];
      w1[kk] = Ws[(k4 * 4 + kk) * 32 + 16 + cg];
    }
    int soff = k4 ^ cr;
#pragma unroll
    for (int i = 0; i < 8; i++) {
      float4 hf = hs[(rg + 16 * i) * 16 + soff];
#pragma unroll
      for (int kk = 0; kk < 4; kk++) {
        float hv = ((const float*)&hf)[kk];
        acc0[i][0] = fmaf(hv, w0[kk].x, acc0[i][0]);
        acc0[i][1] = fmaf(hv, w0[kk].y, acc0[i][1]);
        acc0[i][2] = fmaf(hv, w0[kk].z, acc0[i][2]);
        acc0[i][3] = fmaf(hv, w0[kk].w, acc0[i][3]);
        acc1[i][0] = fmaf(hv, w1[kk].x, acc1[i][0]);
        acc1[i][1] = fmaf(hv, w1[kk].y, acc1[i][1]);
        acc1[i][2] = fmaf(hv, w1[kk].z, acc1[i][2]);
        acc1[i][3] = fmaf(hv, w1[kk].w, acc1[i][3]);
      }
    }
  }
  // ---- store
  float4* ox = (float4*)hx;
#pragma unroll
  for (int i = 0; i < 8; i++) {
    int grow = r0 + rg + 16 * i;
    float4 s0, s1;
    s0.x = acc0[i][0]; s0.y = acc0[i][1]; s0.z = acc0[i][2]; s0.w = acc0[i][3];
    s1.x = acc1[i][0]; s1.y = acc1[i][1]; s1.z = acc1[i][2]; s1.w = acc1[i][3];
    ox[(size_t)grow * 32 + cg] = s0;
    ox[(size_t)grow * 32 + 16 + cg] = s1;
  }
}

// ---------------------------------------------------------------- edge aggregation
// One wave per destination node; lane&31 owns features [4q..4q+3] via float4.
// Two 32-lane halves process two edge streams; each half unrolled 4x ->
// 8 independent 512B row gathers in flight per wave. Halves combined via
// shfl_xor(32). BN partials: LDS block reduce -> one global atomic/feature.
__global__ __launch_bounds__(256) void agg_kernel(
    const float* __restrict__ hx, const int* __restrict__ csr_off,
    const int* __restrict__ src_pack, const float* __restrict__ enorm,
    const float* __restrict__ bond, const float* __restrict__ root,
    const float* __restrict__ deg, float* __restrict__ h2,
    float* __restrict__ bnbuf) {
  __shared__ float4 bondS[NBOND * 32];
  __shared__ float4 rootS[32];
  __shared__ float sbn[256];
  int t = threadIdx.x;
  if (t < NBOND * 32) bondS[t] = ((const float4*)bond)[t];
  if (t < 32) rootS[t] = ((const float4*)root)[t];
  sbn[t] = 0.0f;
  __syncthreads();

  int lane = t & 63;
  int laneq = lane & 31;   // feature quad owner
  int half = lane >> 5;    // which edge stream of the pair
  int wid = t >> 6;
  int gw = blockIdx.x * 4 + wid;
  int nw = gridDim.x * 4;
  const float4* hx4 = (const float4*)hx;
  float4* h24 = (float4*)h2;

  float s0 = 0.f, s1 = 0.f, s2 = 0.f, s3 = 0.f;
  float q0 = 0.f, q1 = 0.f, q2 = 0.f, q3 = 0.f;
  for (int n = gw; n < N_NODES; n += nw) {
    int e0 = csr_off[n], e1 = csr_off[n + 1];
    float a0 = 0.f, a1 = 0.f, a2 = 0.f, a3 = 0.f;
    int e = e0 + half;
    // unrolled 4x: edges e, e+2, e+4, e+6 for this half-wave
    for (; e + 6 < e1; e += 8) {
      int sp0 = src_pack[e];
      int sp1 = src_pack[e + 2];
      int sp2 = src_pack[e + 4];
      int sp3 = src_pack[e + 6];
      float nr0 = enorm[e];
      float nr1 = enorm[e + 2];
      float nr2 = enorm[e + 4];
      float nr3 = enorm[e + 6];
      float4 v0 = hx4[(size_t)(sp0 & 0xFFFFF) * 32 + laneq];
      float4 v1 = hx4[(size_t)(sp1 & 0xFFFFF) * 32 + laneq];
      float4 v2 = hx4[(size_t)(sp2 & 0xFFFFF) * 32 + laneq];
      float4 v3 = hx4[(size_t)(sp3 & 0xFFFFF) * 32 + laneq];
      float4 b0 = bondS[(sp0 >> 20) * 32 + laneq];
      float4 b1 = bondS[(sp1 >> 20) * 32 + laneq];
      float4 b2 = bondS[(sp2 >> 20) * 32 + laneq];
      float4 b3 = bondS[(sp3 >> 20) * 32 + laneq];
      a0 = fmaf(nr0, fmaxf(v0.x + b0.x, 0.f), a0);
      a1 = fmaf(nr0, fmaxf(v0.y + b0.y, 0.f), a1);
      a2 = fmaf(nr0, fmaxf(v0.z + b0.z, 0.f), a2);
      a3 = fmaf(nr0, fmaxf(v0.w + b0.w, 0.f), a3);
      a0 = fmaf(nr1, fmaxf(v1.x + b1.x, 0.f), a0);
      a1 = fmaf(nr1, fmaxf(v1.y + b1.y, 0.f), a1);
      a2 = fmaf(nr1, fmaxf(v1.z + b1.z, 0.f), a2);
      a3 = fmaf(nr1, fmaxf(v1.w + b1.w, 0.f), a3);
      a0 = fmaf(nr2, fmaxf(v2.x + b2.x, 0.f), a0);
      a1 = fmaf(nr2, fmaxf(v2.y + b2.y, 0.f), a1);
      a2 = fmaf(nr2, fmaxf(v2.z + b2.z, 0.f), a2);
      a3 = fmaf(nr2, fmaxf(v2.w + b2.w, 0.f), a3);
      a0 = fmaf(nr3, fmaxf(v3.x + b3.x, 0.f), a0);
      a1 = fmaf(nr3, fmaxf(v3.y + b3.y, 0.f), a1);
      a2 = fmaf(nr3, fmaxf(v3.z + b3.z, 0.f), a2);
      a3 = fmaf(nr3, fmaxf(v3.w + b3.w, 0.f), a3);
    }
    for (; e < e1; e += 2) {
      int sp = src_pack[e];
      float nrm = enorm[e];
      float4 v = hx4[(size_t)(sp & 0xFFFFF) * 32 + laneq];
      float4 eb = bondS[(sp >> 20) * 32 + laneq];
      a0 = fmaf(nrm, fmaxf(v.x + eb.x, 0.f), a0);
      a1 = fmaf(nrm, fmaxf(v.y + eb.y, 0.f), a1);
      a2 = fmaf(nrm, fmaxf(v.z + eb.z, 0.f), a2);
      a3 = fmaf(nrm, fmaxf(v.w + eb.w, 0.f), a3);
    }
    // combine the two halves (lane l and l^32 hold partials for same features)
    a0 += __shfl_xor(a0, 32, 64);
    a1 += __shfl_xor(a1, 32, 64);
    a2 += __shfl_xor(a2, 32, 64);
    a3 += __shfl_xor(a3, 32, 64);
    if (half == 0) {
      float inv = 1.0f / deg[n];
      float4 v = hx4[(size_t)n * 32 + laneq];
      float4 r = rootS[laneq];
      a0 += fmaxf(v.x + r.x, 0.f) * inv;
      a1 += fmaxf(v.y + r.y, 0.f) * inv;
      a2 += fmaxf(v.z + r.z, 0.f) * inv;
      a3 += fmaxf(v.w + r.w, 0.f) * inv;
      float4 o;
      o.x = a0; o.y = a1; o.z = a2; o.w = a3;
      h24[(size_t)n * 32 + laneq] = o;
      s0 += a0; s1 += a1; s2 += a2; s3 += a3;
      q0 += a0 * a0; q1 += a1 * a1; q2 += a2 * a2; q3 += a3 * a3;
    }
  }
  // block-level BN reduction: LDS atomics, then one global atomic per feature
  if (half == 0) {
    int f = 4 * laneq;
    atomicAdd(&sbn[f + 0], s0);
    atomicAdd(&sbn[f + 1], s1);
    atomicAdd(&sbn[f + 2], s2);
    atomicAdd(&sbn[f + 3], s3);
    atomicAdd(&sbn[128 + f + 0], q0);
    atomicAdd(&sbn[128 + f + 1], q1);
    atomicAdd(&sbn[128 + f + 2], q2);
    atomicAdd(&sbn[128 + f + 3], q3);
  }
  __syncthreads();
  atomicAdd(&bnbuf[t], sbn[t]);
}

// ---------------------------------------------------------------- BN finalize
__global__ __launch_bounds__(128) void bnfin_kernel(
    const float* __restrict__ bnbuf, const float* __restrict__ gamma,
    const float* __restrict__ beta, float* __restrict__ scale,
    float* __restrict__ shift) {
  int d = threadIdx.x;
  const float invN = 1.0f / (float)N_NODES;
  float mu = bnbuf[d] * invN;
  float ex2 = bnbuf[128 + d] * invN;
  float var = ex2 - mu * mu;
  float inv = rsqrtf(var + BN_EPS);
  float sc = gamma[d] * inv;
  scale[d] = sc;
  shift[d] = fmaf(-mu, sc, beta[d]);
}

// ---------------------------------------------------------------- pooling (batch is sorted)
__global__ __launch_bounds__(256) void pool_kernel(
    const float* __restrict__ h2, const int* __restrict__ batch,
    const float* __restrict__ scale, const float* __restrict__ shift,
    float* __restrict__ pool, float* __restrict__ pcnt) {
  int t = threadIdx.x;
  int lane = t & 63;
  int wid = t >> 6;
  int gw = blockIdx.x * 4 + wid;
  int nw = gridDim.x * 4;
  int chunk = (N_NODES + nw - 1) / nw;
  int n0 = gw * chunk;
  int n1 = min(n0 + chunk, N_NODES);
  if (n0 >= N_NODES) return;
  const float2* h22 = (const float2*)h2;
  int f0 = 2 * lane, f1 = f0 + 1;
  float sc0 = scale[f0], sc1 = scale[f1], sh0 = shift[f0], sh1 = shift[f1];
  int curg = batch[n0];
  float a0 = 0.f, a1 = 0.f, c = 0.f;
  for (int n = n0; n < n1; n++) {
    int g = batch[n];
    if (g != curg) {
      atomicAdd(&pool[curg * DIM + f0], a0);
      atomicAdd(&pool[curg * DIM + f1], a1);
      if (lane == 0) atomicAdd(&pcnt[curg], c);
      a0 = a1 = c = 0.f;
      curg = g;
    }
    float2 v = h22[(size_t)n * 64 + lane];
    a0 += fmaxf(fmaf(v.x, sc0, sh0), 0.f);
    a1 += fmaxf(fmaf(v.y, sc1, sh1), 0.f);
    c += 1.0f;
  }
  atomicAdd(&pool[curg * DIM + f0], a0);
  atomicAdd(&pool[curg * DIM + f1], a1);
  if (lane == 0) atomicAdd(&pcnt[curg], c);
}

// ---------------------------------------------------------------- output head
__global__ __launch_bounds__(256) void out_kernel(
    const float* __restrict__ pool, const float* __restrict__ pcnt,
    const float* __restrict__ Wout, const float* __restrict__ bout,
    float* __restrict__ out) {
  int idx = blockIdx.x * blockDim.x + threadIdx.x;
  if (idx >= NGRAPH * NTASK) return;
  int g = idx / NTASK, tt = idx % NTASK;
  float inv = 1.0f / fmaxf(pcnt[g], 1.0f);
  float acc = bout[tt];
  for (int d = 0; d < DIM; d++)
    acc = fmaf(pool[g * DIM + d] * inv, Wout[d * NTASK + tt], acc);
  out[idx] = acc;
}

// ----------------------------------------------------------------
extern "C" void kernel_launch(void* const* d_in, const int* in_sizes, int n_in,
                              void* d_out, int out_size, void* d_ws, size_t ws_size,
                              hipStream_t stream) {
  const float* x     = (const float*)d_in[0];
  const int*   eidx  = (const int*)d_in[1];
  const int*   row   = eidx;
  const int*   col   = eidx + N_EDGES;
  const int*   eattr = (const int*)d_in[2];
  const int*   batch = (const int*)d_in[3];
  const float* W     = (const float*)d_in[4];
  const float* b     = (const float*)d_in[5];
  const float* root  = (const float*)d_in[6];
  const float* bond  = (const float*)d_in[7];
  const float* gamma = (const float*)d_in[8];
  const float* beta  = (const float*)d_in[9];
  const float* Wout  = (const float*)d_in[10];
  const float* bout  = (const float*)d_in[11];
  float* out = (float*)d_out;

  // bump allocator over workspace (needs ~170 MB)
  char* w = (char*)d_ws;
  size_t off = 0;
  auto alloc = [&](size_t bytes) -> void* {
    void* p = w + off;
    off = (off + bytes + 511) & ~(size_t)511;
    return p;
  };
  // zero-init region (single memset): histograms, scatter positions, pool accumulators
  int*   cnt_row = (int*)alloc(N_NODES * 4);
  int*   cnt_col = (int*)alloc(N_NODES * 4);
  int*   pos     = (int*)alloc(N_NODES * 4);
  float* pool    = (float*)alloc(NGRAPH * DIM * 4);
  float* pcnt    = (float*)alloc(NGRAPH * 4);
  size_t zbytes  = off;
  // rest
  int*   csr     = (int*)alloc((N_NODES + 1) * 4);
  int*   bsum    = (int*)alloc(512 * 4);
  int*   bexcl   = (int*)alloc(512 * 4);
  float* deg     = (float*)alloc(N_NODES * 4);
  float* dinv    = (float*)alloc(N_NODES * 4);
  int*   spck    = (int*)alloc((size_t)N_EDGES * 4);
  float* enorm   = (float*)alloc((size_t)N_EDGES * 4);
  float* hx      = (float*)alloc((size_t)N_NODES * DIM * 4);
  float* hA      = (float*)alloc((size_t)N_NODES * DIM * 4);
  float* hB      = (float*)alloc((size_t)N_NODES * DIM * 4);
  float* bnbuf   = (float*)alloc(256 * 4);
  float* bnscale = (float*)alloc(DIM * 4);
  float* bnshift = (float*)alloc(DIM * 4);

  hipMemsetAsync(d_ws, 0, zbytes, stream);

  hist_kernel<<<2048, 256, 0, stream>>>(row, col, cnt_row, cnt_col);
  deg_kernel<<<(N_NODES + 255) / 256, 256, 0, stream>>>(cnt_row, deg, dinv);
  const int nb = (N_NODES + 255) / 256;  // 391
  scan1_kernel<<<nb, 256, 0, stream>>>(cnt_col, csr, bsum);
  scan2_kernel<<<1, 512, 0, stream>>>(bsum, bexcl, nb);
  scan3_kernel<<<nb, 256, 0, stream>>>(csr, bexcl);
  scatter_kernel<<<2048, 256, 0, stream>>>(row, col, eattr, csr, pos, dinv, spck, enorm);

  const int gblocks = (N_NODES + GBM - 1) / GBM;  // 782
  const float* hin = x;
  for (int l = 0; l < NLAYER; l++) {
    float* h2 = (l % 2 == 0) ? hA : hB;
    gemm_kernel<<<gblocks, 256, 0, stream>>>(
        hin, W + (size_t)l * DIM * DIM, b + l * DIM,
        bnscale, bnshift, (l > 0) ? 1 : 0, hx, bnbuf);
    agg_kernel<<<2048, 256, 0, stream>>>(
        hx, csr, spck, enorm, bond + (size_t)l * NBOND * DIM, root + l * DIM,
        deg, h2, bnbuf);
    bnfin_kernel<<<1, 128, 0, stream>>>(bnbuf, gamma + l * DIM, beta + l * DIM,
                                        bnscale, bnshift);
    hin = h2;
  }
  pool_kernel<<<256, 256, 0, stream>>>(hin, batch, bnscale, bnshift, pool, pcnt);
  out_kernel<<<5, 256, 0, stream>>>(pool, pcnt, Wout, bout, out);
}